// Round 1
// baseline (154.936 us; speedup 1.0000x reference)
//
#include <hip/hip_runtime.h>

#define WI 512
#define HI 512
#define WO 2048
#define HO 2048
#define NIMG 8
#define CCH 3
#define EPS 1e-8f
#define ROWS 8

// ---------------------------------------------------------------------------
// Pre-kernel: compute per-image affine params (a, tx, b, ty) from coor.
// 8 images x 4 sigmoids = 32 expf total; keeps transcendentals out of the
// 4.2M-thread main kernel.
// ---------------------------------------------------------------------------
__global__ void diffcomp_params(const float* __restrict__ coor,
                                float4* __restrict__ params) {
    int n = threadIdx.x;
    if (n < NIMG) {
        float cx = coor[n * 4 + 0];
        float cy = coor[n * 4 + 1];
        float cw = coor[n * 4 + 2];
        float ch = coor[n * 4 + 3];
        // sigmoid
        float x = (1.0f / (1.0f + expf(-cx))) * (float)WO;
        float y = (1.0f / (1.0f + expf(-cy))) * (float)HO;
        float w = (1.0f / (1.0f + expf(-cw))) * (float)WO;
        float h = (1.0f / (1.0f + expf(-ch))) * (float)HO;
        float a  = (float)WO / (w + EPS);
        float tx = (2.0f / (float)WO) * ((float)WO * 0.5f - x) * a;
        float b  = (float)HO / (h + EPS);
        float ty = (2.0f / (float)HO) * ((float)HO * 0.5f - y) * b;
        params[n] = make_float4(a, tx, b, ty);
    }
}

// ---------------------------------------------------------------------------
// Main kernel: tile = 256 wo  x  ROWS ho per block. One thread per column.
// X-side bilinear params computed once per thread (registers, unrolled over
// the 8 images); y-side recomputed per row (wave-uniform). Gathers skipped
// entirely where the mask is zero (bit-exact: bg*(1-0)+s*0 == bg).
// ---------------------------------------------------------------------------
__launch_bounds__(256)
__global__ void diffcomp_main(const float* __restrict__ src,
                              const float* __restrict__ bg,
                              const float4* __restrict__ params,
                              float* __restrict__ out) {
    const int wo  = blockIdx.x * 256 + threadIdx.x;
    const int ho0 = blockIdx.y * ROWS;

    float4 P[NIMG];
#pragma unroll
    for (int n = 0; n < NIMG; n++) P[n] = params[n];

    // ---- x-side (depends only on wo) ----
    float wxv0[NIMG], wxv1[NIMG], mx[NIMG];
    int   x0c[NIMG], x1c[NIMG];
    const float xs = (2.0f * (float)wo + 1.0f) / (float)WO - 1.0f;
#pragma unroll
    for (int n = 0; n < NIMG; n++) {
        float a  = P[n].x, tx = P[n].y;
        float gx = a * xs + tx;
        float ix = (((gx + 1.0f) * (float)WI) - 1.0f) * 0.5f;
        float x0f = floorf(ix);
        float wx1 = ix - x0f;
        float wx0 = 1.0f - wx1;
        float x1f = x0f + 1.0f;
        float vx0 = (x0f >= 0.0f && x0f < (float)WI) ? 1.0f : 0.0f;
        float vx1 = (x1f >= 0.0f && x1f < (float)WI) ? 1.0f : 0.0f;
        wxv0[n] = wx0 * vx0;
        wxv1[n] = wx1 * vx1;
        x0c[n] = (int)fminf(fmaxf(x0f, 0.0f), (float)(WI - 1));
        x1c[n] = (int)fminf(fmaxf(x1f, 0.0f), (float)(WI - 1));
        mx[n] = wxv0[n] + wxv1[n];
    }

    for (int r = 0; r < ROWS; r++) {
        const int ho = ho0 + r;
        const float ys = (2.0f * (float)ho + 1.0f) / (float)HO - 1.0f;
        const int pix = ho * WO + wo;

        float acc0 = bg[0 * HO * WO + pix];
        float acc1 = bg[1 * HO * WO + pix];
        float acc2 = bg[2 * HO * WO + pix];

#pragma unroll
        for (int n = 0; n < NIMG; n++) {
            float b  = P[n].z, ty = P[n].w;
            float gy = b * ys + ty;
            float iy = (((gy + 1.0f) * (float)HI) - 1.0f) * 0.5f;
            float y0f = floorf(iy);
            float wy1 = iy - y0f;
            float wy0 = 1.0f - wy1;
            float y1f = y0f + 1.0f;
            float vy0 = (y0f >= 0.0f && y0f < (float)HI) ? 1.0f : 0.0f;
            float vy1 = (y1f >= 0.0f && y1f < (float)HI) ? 1.0f : 0.0f;
            float wyv0 = wy0 * vy0;
            float wyv1 = wy1 * vy1;
            float my = wyv0 + wyv1;
            float m  = my * mx[n];
            if (m > 0.0f) {
                int y0i = (int)fminf(fmaxf(y0f, 0.0f), (float)(HI - 1));
                int y1i = (int)fminf(fmaxf(y1f, 0.0f), (float)(HI - 1));
                const float* ib = src + n * (CCH * HI * WI);
                const int o00 = y0i * WI + x0c[n];
                const int o01 = y0i * WI + x1c[n];
                const int o10 = y1i * WI + x0c[n];
                const int o11 = y1i * WI + x1c[n];
                const float om = 1.0f - m;
                float s0, s1, s2;
                {
                    const float* p = ib + 0 * HI * WI;
                    float v00 = p[o00], v01 = p[o01], v10 = p[o10], v11 = p[o11];
                    s0 = (v00 * wyv0 + v10 * wyv1) * wxv0[n]
                       + (v01 * wyv0 + v11 * wyv1) * wxv1[n];
                }
                {
                    const float* p = ib + 1 * HI * WI;
                    float v00 = p[o00], v01 = p[o01], v10 = p[o10], v11 = p[o11];
                    s1 = (v00 * wyv0 + v10 * wyv1) * wxv0[n]
                       + (v01 * wyv0 + v11 * wyv1) * wxv1[n];
                }
                {
                    const float* p = ib + 2 * HI * WI;
                    float v00 = p[o00], v01 = p[o01], v10 = p[o10], v11 = p[o11];
                    s2 = (v00 * wyv0 + v10 * wyv1) * wxv0[n]
                       + (v01 * wyv0 + v11 * wyv1) * wxv1[n];
                }
                acc0 = acc0 * om + s0 * m;
                acc1 = acc1 * om + s1 * m;
                acc2 = acc2 * om + s2 * m;
            }
        }

        out[0 * HO * WO + pix] = acc0;
        out[1 * HO * WO + pix] = acc1;
        out[2 * HO * WO + pix] = acc2;
    }
}

extern "C" void kernel_launch(void* const* d_in, const int* in_sizes, int n_in,
                              void* d_out, int out_size, void* d_ws, size_t ws_size,
                              hipStream_t stream) {
    const float* src  = (const float*)d_in[0];   // [8,3,512,512]
    const float* bg   = (const float*)d_in[1];   // [1,3,2048,2048]
    const float* coor = (const float*)d_in[2];   // [8,4]
    float* out = (float*)d_out;                  // [1,3,2048,2048]
    float4* params = (float4*)d_ws;              // 8 * float4 = 128 B

    hipLaunchKernelGGL(diffcomp_params, dim3(1), dim3(64), 0, stream, coor, params);
    dim3 grid(WO / 256, HO / ROWS);
    hipLaunchKernelGGL(diffcomp_main, grid, dim3(256), 0, stream,
                       src, bg, params, out);
}